// Round 6
// baseline (258.715 us; speedup 1.0000x reference)
//
#include <hip/hip_runtime.h>

// Fused EdgeNetwork, 2-deep software-pipelined persistent waves.
//   OUT = P @ W on MFMA:  P[e, b*32+j] = bond[e,b]*nb[e,j]  (b=16 -> bias row)
//   W[b*32+j, i] = K[b, i*32+j]  held in 68 VGPRs per wave (col-half split).
// R6 change vs R5: 6 blocks/CU (grid 1536, launch_bounds(256,6)) -- R5 ran at
// 3 blocks/CU with 80 VGPRs, starving the SIMDs (Occupancy 24%).

typedef _Float16 half8 __attribute__((ext_vector_type(8)));
typedef _Float16 half4t __attribute__((ext_vector_type(4)));
typedef float float4v __attribute__((ext_vector_type(4)));

constexpr int NA = 100000;
constexpr int E  = 400000;
constexpr int TILES = E / 32;          // 12500
constexpr int NBLK  = 1536;            // 6 blocks/CU
constexpr int HALFW = NBLK * 4 / 2;    // 3072 waves per column-half

constexpr size_t OFF_ATOMH = 0;                   // _Float16[NA*32]  (6.4 MB)
constexpr size_t OFF_BONDH = (size_t)NA * 32 * 2; // _Float16[E*16]  (12.8 MB)

constexpr int NZ4 = NA * 32 / 4;   // out zeroing, float4 units
constexpr int NA4 = NA * 32 / 4;   // atom convert, float4 units
constexpr int NB4 = E * 16 / 4;    // bond convert, float4 units
constexpr int PREP_TOT = NZ4 + NA4 + NB4;

__global__ void k_prep(const float* __restrict__ atom,
                       const float* __restrict__ bond,
                       float4* __restrict__ outz,
                       half4t* __restrict__ atomh4,
                       half4t* __restrict__ bondh4) {
  int i = blockIdx.x * blockDim.x + threadIdx.x;
  if (i < NZ4) {
    outz[i] = make_float4(0.f, 0.f, 0.f, 0.f);
  } else if (i < NZ4 + NA4) {
    int k = i - NZ4;
    float4 v = ((const float4*)atom)[k];
    half4t hh = { (_Float16)v.x, (_Float16)v.y, (_Float16)v.z, (_Float16)v.w };
    atomh4[k] = hh;
  } else if (i < PREP_TOT) {
    int k = i - NZ4 - NA4;
    float4 v = ((const float4*)bond)[k];
    half4t hh = { (_Float16)v.x, (_Float16)v.y, (_Float16)v.z, (_Float16)v.w };
    bondh4[k] = hh;
  }
}

static __device__ inline half8 splat8(_Float16 v) {
  half8 r = {v, v, v, v, v, v, v, v};
  return r;
}

__global__ __launch_bounds__(256, 6)
void edge_fused(const _Float16* __restrict__ atomh,
                const _Float16* __restrict__ bondh,
                const int* __restrict__ pairs,
                const float* __restrict__ Kmat,
                const float* __restrict__ bias,
                float* __restrict__ out)
{
  const int tid  = threadIdx.x;
  const int lane = tid & 63;
  const int wid  = blockIdx.x * 4 + (tid >> 6);
  const int h    = wid & 1;          // column half this wave owns
  const int q    = lane >> 4;
  const int el   = lane & 15;
  const int n    = el + h * 16;      // output column
  const int j0   = q * 8;

  // W fragments for all 17 K-steps, register-resident.
  half8 Wr[17];
  #pragma unroll
  for (int s = 0; s < 17; ++s) {
    const float* src = (s < 16) ? (Kmat + s * 1024 + n * 32 + j0)
                                : (bias + n * 32 + j0);
    half8 w;
    #pragma unroll
    for (int j = 0; j < 8; ++j) w[j] = (_Float16)src[j];
    Wr[s] = w;
  }

  const int start  = wid >> 1;
  const int stride = HALFW;
  const int2* pairs2 = (const int2*)pairs;

  auto ldpv = [&](int t) -> int2 {
    const int tc = t < TILES ? t : TILES - 1;   // clamp: loads stay valid
    int2 v = make_int2(0, 0);
    if (lane < 32) v = pairs2[tc * 32 + lane];
    return v;
  };

  if (start >= TILES) return;

  // ---- Pipeline prologue: stage tile `start`, start indices for start+stride.
  int2 pv0 = ldpv(start);
  int2 pv1 = ldpv(start + stride);

  half8 nbA_c, nbB_c, bA0_c, bA1_c, bB0_c, bB1_c;
  {
    const int aA = __shfl(pv0.y, el);
    const int aB = __shfl(pv0.y, el + 16);
    nbA_c = *(const half8*)(atomh + (size_t)aA * 32 + j0);
    nbB_c = *(const half8*)(atomh + (size_t)aB * 32 + j0);
    const _Float16* brA = bondh + (size_t)(start * 32 + el) * 16;
    const _Float16* brB = bondh + (size_t)(start * 32 + el + 16) * 16;
    bA0_c = *(const half8*)(brA);  bA1_c = *(const half8*)(brA + 8);
    bB0_c = *(const half8*)(brB);  bB1_c = *(const half8*)(brB + 8);
  }

  for (int t = start; t < TILES; t += stride) {
    const int tn = t + stride;

    // ---- Stage next tile first (loads in flight across this tile's compute).
    half8 nbA_n, nbB_n, bA0_n, bA1_n, bB0_n, bB1_n;
    {
      const int aA = __shfl(pv1.y, el);
      const int aB = __shfl(pv1.y, el + 16);
      nbA_n = *(const half8*)(atomh + (size_t)aA * 32 + j0);
      nbB_n = *(const half8*)(atomh + (size_t)aB * 32 + j0);
      const int tc = tn < TILES ? tn : TILES - 1;
      const _Float16* brA = bondh + (size_t)(tc * 32 + el) * 16;
      const _Float16* brB = bondh + (size_t)(tc * 32 + el + 16) * 16;
      bA0_n = *(const half8*)(brA);  bA1_n = *(const half8*)(brA + 8);
      bB0_n = *(const half8*)(brB);  bB1_n = *(const half8*)(brB + 8);
    }
    const int2 pv2 = ldpv(tn + stride);

    // ---- Compute current tile.
    float4v acc0 = {0.f, 0.f, 0.f, 0.f};
    float4v acc1 = {0.f, 0.f, 0.f, 0.f};
    #pragma unroll
    for (int s = 0; s < 16; ++s) {
      const _Float16 sA = (s < 8) ? bA0_c[s] : bA1_c[s - 8];
      const _Float16 sB = (s < 8) ? bB0_c[s] : bB1_c[s - 8];
      const half8 aAf = nbA_c * splat8(sA);
      const half8 aBf = nbB_c * splat8(sB);
      acc0 = __builtin_amdgcn_mfma_f32_16x16x32_f16(aAf, Wr[s], acc0, 0, 0, 0);
      acc1 = __builtin_amdgcn_mfma_f32_16x16x32_f16(aBf, Wr[s], acc1, 0, 0, 0);
    }
    acc0 = __builtin_amdgcn_mfma_f32_16x16x32_f16(nbA_c, Wr[16], acc0, 0, 0, 0);
    acc1 = __builtin_amdgcn_mfma_f32_16x16x32_f16(nbB_c, Wr[16], acc1, 0, 0, 0);

    // ---- Epilogue: fire-and-forget atomics for current tile.
    #pragma unroll
    for (int r = 0; r < 4; ++r) {
      const int s0 = __shfl(pv0.x, q * 4 + r);
      atomicAdd(out + (size_t)s0 * 32 + n, acc0[r]);
      const int s1 = __shfl(pv0.x, q * 4 + r + 16);
      atomicAdd(out + (size_t)s1 * 32 + n, acc1[r]);
    }

    // ---- Rotate pipeline registers.
    pv0 = pv1; pv1 = pv2;
    nbA_c = nbA_n; nbB_c = nbB_n;
    bA0_c = bA0_n; bA1_c = bA1_n; bB0_c = bB0_n; bB1_c = bB1_n;
  }
}

extern "C" void kernel_launch(void* const* d_in, const int* in_sizes, int n_in,
                              void* d_out, int out_size, void* d_ws, size_t ws_size,
                              hipStream_t stream) {
  const float* atom  = (const float*)d_in[0];   // (100000, 32) f32
  const float* bondf = (const float*)d_in[1];   // (400000, 16) f32
  const int*   pairs = (const int*)d_in[2];     // (400000, 2) int32
  const float* Kmat  = (const float*)d_in[3];   // (16, 1024) f32
  const float* bias  = (const float*)d_in[4];   // (1024,) f32
  float* out = (float*)d_out;                   // (100000, 32) f32

  _Float16* atomh = (_Float16*)((char*)d_ws + OFF_ATOMH);
  _Float16* bondh = (_Float16*)((char*)d_ws + OFF_BONDH);

  k_prep<<<(PREP_TOT + 255) / 256, 256, 0, stream>>>(
      atom, bondf, (float4*)out, (half4t*)atomh, (half4t*)bondh);
  edge_fused<<<NBLK, 256, 0, stream>>>(atomh, bondh, pairs, Kmat, bias, out);
}

// Round 7
// 143.286 us; speedup vs baseline: 1.8056x; 1.8056x over previous
//
#include <hip/hip_runtime.h>

// Fused EdgeNetwork, 2-deep software-pipelined persistent waves.
//   OUT = P @ W on MFMA:  P[e, b*32+j] = bond[e,b]*nb[e,j]  (b=16 -> bias row)
//   W[b*32+j, i] = K[b, i*32+j]  held in 68 VGPRs per wave (col-half split).
// R7 = R5 kernel verbatim (launch_bounds(256,3): 80 VGPRs, no spill) but grid
// 1536 blocks. R6's launch_bounds(256,6) capped VGPRs at 40 -> scratch spill
// (FETCH 25->310 MB). Occupancy comes from actual usage: 80 VGPRs = 6 w/SIMD.

typedef _Float16 half8 __attribute__((ext_vector_type(8)));
typedef _Float16 half4t __attribute__((ext_vector_type(4)));
typedef float float4v __attribute__((ext_vector_type(4)));

constexpr int NA = 100000;
constexpr int E  = 400000;
constexpr int TILES = E / 32;          // 12500
constexpr int NBLK  = 1536;            // 6 blocks/CU by VGPR usage (80)
constexpr int HALFW = NBLK * 4 / 2;    // 3072 waves per column-half

constexpr size_t OFF_ATOMH = 0;                   // _Float16[NA*32]  (6.4 MB)
constexpr size_t OFF_BONDH = (size_t)NA * 32 * 2; // _Float16[E*16]  (12.8 MB)

constexpr int NZ4 = NA * 32 / 4;   // out zeroing, float4 units
constexpr int NA4 = NA * 32 / 4;   // atom convert, float4 units
constexpr int NB4 = E * 16 / 4;    // bond convert, float4 units
constexpr int PREP_TOT = NZ4 + NA4 + NB4;

__global__ void k_prep(const float* __restrict__ atom,
                       const float* __restrict__ bond,
                       float4* __restrict__ outz,
                       half4t* __restrict__ atomh4,
                       half4t* __restrict__ bondh4) {
  int i = blockIdx.x * blockDim.x + threadIdx.x;
  if (i < NZ4) {
    outz[i] = make_float4(0.f, 0.f, 0.f, 0.f);
  } else if (i < NZ4 + NA4) {
    int k = i - NZ4;
    float4 v = ((const float4*)atom)[k];
    half4t hh = { (_Float16)v.x, (_Float16)v.y, (_Float16)v.z, (_Float16)v.w };
    atomh4[k] = hh;
  } else if (i < PREP_TOT) {
    int k = i - NZ4 - NA4;
    float4 v = ((const float4*)bond)[k];
    half4t hh = { (_Float16)v.x, (_Float16)v.y, (_Float16)v.z, (_Float16)v.w };
    bondh4[k] = hh;
  }
}

static __device__ inline half8 splat8(_Float16 v) {
  half8 r = {v, v, v, v, v, v, v, v};
  return r;
}

__global__ __launch_bounds__(256, 3)
void edge_fused(const _Float16* __restrict__ atomh,
                const _Float16* __restrict__ bondh,
                const int* __restrict__ pairs,
                const float* __restrict__ Kmat,
                const float* __restrict__ bias,
                float* __restrict__ out)
{
  const int tid  = threadIdx.x;
  const int lane = tid & 63;
  const int wid  = blockIdx.x * 4 + (tid >> 6);
  const int h    = wid & 1;          // column half this wave owns
  const int q    = lane >> 4;
  const int el   = lane & 15;
  const int n    = el + h * 16;      // output column
  const int j0   = q * 8;

  // W fragments for all 17 K-steps, register-resident.
  half8 Wr[17];
  #pragma unroll
  for (int s = 0; s < 17; ++s) {
    const float* src = (s < 16) ? (Kmat + s * 1024 + n * 32 + j0)
                                : (bias + n * 32 + j0);
    half8 w;
    #pragma unroll
    for (int j = 0; j < 8; ++j) w[j] = (_Float16)src[j];
    Wr[s] = w;
  }

  const int start  = wid >> 1;
  const int stride = HALFW;
  const int2* pairs2 = (const int2*)pairs;

  auto ldpv = [&](int t) -> int2 {
    const int tc = t < TILES ? t : TILES - 1;   // clamp: loads stay valid
    int2 v = make_int2(0, 0);
    if (lane < 32) v = pairs2[tc * 32 + lane];
    return v;
  };

  if (start >= TILES) return;

  // ---- Pipeline prologue: stage tile `start`, start indices for start+stride.
  int2 pv0 = ldpv(start);
  int2 pv1 = ldpv(start + stride);

  half8 nbA_c, nbB_c, bA0_c, bA1_c, bB0_c, bB1_c;
  {
    const int aA = __shfl(pv0.y, el);
    const int aB = __shfl(pv0.y, el + 16);
    nbA_c = *(const half8*)(atomh + (size_t)aA * 32 + j0);
    nbB_c = *(const half8*)(atomh + (size_t)aB * 32 + j0);
    const _Float16* brA = bondh + (size_t)(start * 32 + el) * 16;
    const _Float16* brB = bondh + (size_t)(start * 32 + el + 16) * 16;
    bA0_c = *(const half8*)(brA);  bA1_c = *(const half8*)(brA + 8);
    bB0_c = *(const half8*)(brB);  bB1_c = *(const half8*)(brB + 8);
  }

  for (int t = start; t < TILES; t += stride) {
    const int tn = t + stride;

    // ---- Stage next tile first (loads in flight across this tile's compute).
    half8 nbA_n, nbB_n, bA0_n, bA1_n, bB0_n, bB1_n;
    {
      const int aA = __shfl(pv1.y, el);
      const int aB = __shfl(pv1.y, el + 16);
      nbA_n = *(const half8*)(atomh + (size_t)aA * 32 + j0);
      nbB_n = *(const half8*)(atomh + (size_t)aB * 32 + j0);
      const int tc = tn < TILES ? tn : TILES - 1;
      const _Float16* brA = bondh + (size_t)(tc * 32 + el) * 16;
      const _Float16* brB = bondh + (size_t)(tc * 32 + el + 16) * 16;
      bA0_n = *(const half8*)(brA);  bA1_n = *(const half8*)(brA + 8);
      bB0_n = *(const half8*)(brB);  bB1_n = *(const half8*)(brB + 8);
    }
    const int2 pv2 = ldpv(tn + stride);

    // ---- Compute current tile.
    float4v acc0 = {0.f, 0.f, 0.f, 0.f};
    float4v acc1 = {0.f, 0.f, 0.f, 0.f};
    #pragma unroll
    for (int s = 0; s < 16; ++s) {
      const _Float16 sA = (s < 8) ? bA0_c[s] : bA1_c[s - 8];
      const _Float16 sB = (s < 8) ? bB0_c[s] : bB1_c[s - 8];
      const half8 aAf = nbA_c * splat8(sA);
      const half8 aBf = nbB_c * splat8(sB);
      acc0 = __builtin_amdgcn_mfma_f32_16x16x32_f16(aAf, Wr[s], acc0, 0, 0, 0);
      acc1 = __builtin_amdgcn_mfma_f32_16x16x32_f16(aBf, Wr[s], acc1, 0, 0, 0);
    }
    acc0 = __builtin_amdgcn_mfma_f32_16x16x32_f16(nbA_c, Wr[16], acc0, 0, 0, 0);
    acc1 = __builtin_amdgcn_mfma_f32_16x16x32_f16(nbB_c, Wr[16], acc1, 0, 0, 0);

    // ---- Epilogue: fire-and-forget atomics for current tile.
    #pragma unroll
    for (int r = 0; r < 4; ++r) {
      const int s0 = __shfl(pv0.x, q * 4 + r);
      atomicAdd(out + (size_t)s0 * 32 + n, acc0[r]);
      const int s1 = __shfl(pv0.x, q * 4 + r + 16);
      atomicAdd(out + (size_t)s1 * 32 + n, acc1[r]);
    }

    // ---- Rotate pipeline registers.
    pv0 = pv1; pv1 = pv2;
    nbA_c = nbA_n; nbB_c = nbB_n;
    bA0_c = bA0_n; bA1_c = bA1_n; bB0_c = bB0_n; bB1_c = bB1_n;
  }
}

extern "C" void kernel_launch(void* const* d_in, const int* in_sizes, int n_in,
                              void* d_out, int out_size, void* d_ws, size_t ws_size,
                              hipStream_t stream) {
  const float* atom  = (const float*)d_in[0];   // (100000, 32) f32
  const float* bondf = (const float*)d_in[1];   // (400000, 16) f32
  const int*   pairs = (const int*)d_in[2];     // (400000, 2) int32
  const float* Kmat  = (const float*)d_in[3];   // (16, 1024) f32
  const float* bias  = (const float*)d_in[4];   // (1024,) f32
  float* out = (float*)d_out;                   // (100000, 32) f32

  _Float16* atomh = (_Float16*)((char*)d_ws + OFF_ATOMH);
  _Float16* bondh = (_Float16*)((char*)d_ws + OFF_BONDH);

  k_prep<<<(PREP_TOT + 255) / 256, 256, 0, stream>>>(
      atom, bondf, (float4*)out, (half4t*)atomh, (half4t*)bondh);
  edge_fused<<<NBLK, 256, 0, stream>>>(atomh, bondh, pairs, Kmat, bias, out);
}